// Round 4
// baseline (340.973 us; speedup 1.0000x reference)
//
#include <hip/hip_runtime.h>
#include <hip/hip_fp16.h>
#include <cmath>

#define NLVL 16
#define TSIZE (1u << 19)
#define HMASK ((1u << 19) - 1u)
#define PRIME1 2654435761u

struct Params {
    float rf[NLVL];
    int   ri[NLVL];
    int   base[NLVL];     // uint2-entry index of level's table inside ws
    int   stride[NLVL];   // ri+1 entries per row (edge clip baked in, no pad)
};

__device__ __forceinline__ unsigned pack_h2(float a, float b) {
    __half2 h = __floats2half2_rn(a, b);
    unsigned u; __builtin_memcpy(&u, &h, 4); return u;
}
__device__ __forceinline__ float2 unpack_h2(unsigned u) {
    __half2 h; __builtin_memcpy(&h, &u, 4); return __half22float2(h);
}

// Dense entry (l,cy,cx) = { cell(cx).feats, cell(min(cx+1,ri)).feats } as 4xfp16
// in one aligned uint2 (8B): single dwordx2 per (level,row), never line-spanning,
// x-edge clip baked into the table. 711,664 entries = 5.69 MiB.
__global__ __launch_bounds__(256) void build_dense(
    const float2* __restrict__ emb, uint2* __restrict__ dense, Params p)
{
    const int l = blockIdx.y;
    const int cy = blockIdx.x;
    const int ri = p.ri[l];
    if (cy > ri) return;
    const unsigned hy = (unsigned)cy * PRIME1;
    const float2* tab = emb + (size_t)l * TSIZE;
    uint2* drow = dense + p.base[l] + (size_t)cy * p.stride[l];
    for (int cx = threadIdx.x; cx <= ri; cx += 256) {
        const float2 e0 = tab[((unsigned)cx ^ hy) & HMASK];
        const unsigned cx1 = (unsigned)min(cx + 1, ri);
        const float2 e1 = tab[(cx1 ^ hy) & HMASK];
        drow[cx] = make_uint2(pack_h2(e0.x, e0.y), pack_h2(e1.x, e1.y));
    }
}

// Main: 32 single-dwordx2 gathers/point on a 5.69MB L2/L3-resident table,
// no LDS, no barrier; per-thread-contiguous 128B output via 8 float4 stores.
__global__ __launch_bounds__(256) void hash_embed_dense(
    const float2* __restrict__ x,
    const uint2* __restrict__ dense,
    float4* __restrict__ out,
    Params p, int n)
{
    const int i = blockIdx.x * 256 + threadIdx.x;
    if (i >= n) return;
    const float2 xy = x[i];
    float4* outp = out + (size_t)i * 8;

    #pragma unroll
    for (int half = 0; half < 2; ++half) {
        uint2 r0[8], r1[8];
        float w0v[8], w1v[8];
        // phase 1: issue all 16 row-loads of this batch
        #pragma unroll
        for (int j = 0; j < 8; ++j) {
            const int l = half * 8 + j;
            const float rf = p.rf[l];
            const int ri = p.ri[l];
            const float px = xy.x * rf, py = xy.y * rf;
            const float fx = floorf(px), fy = floorf(py);
            w0v[j] = px - fx;
            w1v[j] = py - fy;
            const int tx = (int)fx, ty = (int)fy;
            const int cx0 = min(tx, ri);          // x*res can round to exactly res
            const int cy0 = min(ty, ri);
            const int cy1 = min(ty + 1, ri);
            const uint2* tab = dense + p.base[l];
            r0[j] = tab[cy0 * p.stride[l] + cx0];
            r1[j] = tab[cy1 * p.stride[l] + cx0];
        }
        // phase 2: blend (reference order) + 4 float4 stores
        #pragma unroll
        for (int j = 0; j < 8; j += 2) {
            float4 v;
            {
                const float w0 = w0v[j], w1 = w1v[j];
                const float u0 = 1.f - w0, u1 = 1.f - w1;
                const float2 e00 = unpack_h2(r0[j].x), e01 = unpack_h2(r0[j].y);
                const float2 e10 = unpack_h2(r1[j].x), e11 = unpack_h2(r1[j].y);
                v.x = (e00.x*u0 + e01.x*w0)*u1 + (e10.x*u0 + e11.x*w0)*w1;
                v.y = (e00.y*u0 + e01.y*w0)*u1 + (e10.y*u0 + e11.y*w0)*w1;
            }
            {
                const float w0 = w0v[j+1], w1 = w1v[j+1];
                const float u0 = 1.f - w0, u1 = 1.f - w1;
                const float2 e00 = unpack_h2(r0[j+1].x), e01 = unpack_h2(r0[j+1].y);
                const float2 e10 = unpack_h2(r1[j+1].x), e11 = unpack_h2(r1[j+1].y);
                v.z = (e00.x*u0 + e01.x*w0)*u1 + (e10.x*u0 + e11.x*w0)*w1;
                v.w = (e00.y*u0 + e01.y*w0)*u1 + (e10.y*u0 + e11.y*w0)*w1;
            }
            outp[half * 4 + j / 2] = v;
        }
    }
}

// Fallback (round-1 structure, fp32 direct hash gathers) if ws is too small.
__global__ __launch_bounds__(256) void hash_embed_direct(
    const float2* __restrict__ x,
    const float2* __restrict__ emb,
    float* __restrict__ out,
    Params p, int n)
{
    const int i = blockIdx.x * 256 + threadIdx.x;
    if (i >= n) return;
    const float2 xy = x[i];
    #pragma unroll
    for (int half = 0; half < 2; ++half) {
        float2 f[32];
        float w0v[8], w1v[8];
        #pragma unroll
        for (int j = 0; j < 8; ++j) {
            const int l = half * 8 + j;
            const float rf = p.rf[l];
            const int ri = p.ri[l];
            const float px = xy.x * rf, py = xy.y * rf;
            const float fx = floorf(px), fy = floorf(py);
            w0v[j] = px - fx; w1v[j] = py - fy;
            const int tx = (int)fx, ty = (int)fy;
            const unsigned cx0 = (unsigned)min(tx, ri);
            const unsigned cy0 = (unsigned)min(ty, ri);
            const unsigned cx1 = (unsigned)min(tx + 1, ri);
            const unsigned cy1 = (unsigned)min(ty + 1, ri);
            const unsigned hy0 = cy0 * PRIME1, hy1 = cy1 * PRIME1;
            const float2* tab = emb + (size_t)l * TSIZE;
            f[j*4+0] = tab[(cx0 ^ hy0) & HMASK];
            f[j*4+1] = tab[(cx1 ^ hy0) & HMASK];
            f[j*4+2] = tab[(cx0 ^ hy1) & HMASK];
            f[j*4+3] = tab[(cx1 ^ hy1) & HMASK];
        }
        #pragma unroll
        for (int j = 0; j < 8; ++j) {
            const int l = half * 8 + j;
            const float w0 = w0v[j], w1 = w1v[j];
            const float u0 = 1.f - w0, u1 = 1.f - w1;
            const float2 f0 = f[j*4+0], f1 = f[j*4+1], f2 = f[j*4+2], f3 = f[j*4+3];
            out[(size_t)i*32 + l*2 + 0] = (f0.x*u0 + f1.x*w0)*u1 + (f2.x*u0 + f3.x*w0)*w1;
            out[(size_t)i*32 + l*2 + 1] = (f0.y*u0 + f1.y*w0)*u1 + (f2.y*u0 + f3.y*w0)*w1;
        }
    }
}

extern "C" void kernel_launch(void* const* d_in, const int* in_sizes, int n_in,
                              void* d_out, int out_size, void* d_ws, size_t ws_size,
                              hipStream_t stream) {
    const float2* x = (const float2*)d_in[0];
    const float2* emb = (const float2*)d_in[1];
    const int n = in_sizes[0] / 2;

    // numpy-exact per-level resolutions (ulp-sensitive floors at l=3,6,9,...)
    Params p;
    int off = 0;
    const double b = std::exp((std::log(512.0) - std::log(16.0)) / 15.0);
    for (int l = 0; l < NLVL; ++l) {
        const double r = std::floor(16.0 * std::pow(b, (double)l));
        p.rf[l] = (float)r;
        p.ri[l] = (int)r;
        p.stride[l] = p.ri[l] + 1;
        p.base[l] = off;
        off += (p.ri[l] + 1) * (p.ri[l] + 1);
    }
    const size_t need = (size_t)off * sizeof(uint2);   // ~5.69 MiB

    const int grid = (n + 255) / 256;
    if (ws_size >= need) {
        build_dense<<<dim3(513, 16), 256, 0, stream>>>(emb, (uint2*)d_ws, p);
        hash_embed_dense<<<grid, 256, 0, stream>>>(x, (const uint2*)d_ws,
                                                   (float4*)d_out, p, n);
    } else {
        hash_embed_direct<<<grid, 256, 0, stream>>>(x, emb, (float*)d_out, p, n);
    }
}